// Round 5
// baseline (688.574 us; speedup 1.0000x reference)
//
#include <hip/hip_runtime.h>

// Problem: N=C=H=W=64. n = N*H*W = 262144 samples per channel.
// ws layout:
//   [0,     32768)  S      double[64*64]   Gram accumulator
//   [32768, 33280)  rowsum double[64]
//   [33280, 49664)  T      float[64*64]    folded transform
//   [49664, 49920)  off    float[64]       folded offset

// Gram + row sums. Grid 512: (n = b>>3, hw eighth = b&7). 4 tiles of 128.
// Tile staged TRANSPOSED: XT[kk][c] so both operand fragments are b128 reads.
__global__ __launch_bounds__(256) void zca_gram_k(const float* __restrict__ x,
                                                  double* __restrict__ S,
                                                  double* __restrict__ rowsum) {
  __shared__ float XT[128 * 72];  // row kk (stride 72), 64 channels
  const int t = threadIdx.x;
  const int n = blockIdx.x >> 3;
  const int k0base = (blockIdx.x & 7) << 9;
  const float* xb = x + ((size_t)n << 18);
  const int cg = t >> 4, dg = t & 15;
  const int sc = t & 63, kq = t >> 6;

  double acc[4][4];
#pragma unroll
  for (int i = 0; i < 4; ++i)
#pragma unroll
    for (int j = 0; j < 4; ++j) acc[i][j] = 0.0;
  double rs[4] = {0.0, 0.0, 0.0, 0.0};

  for (int tile = 0; tile < 4; ++tile) {
    const int k0 = k0base + (tile << 7);
#pragma unroll
    for (int r = 0; r < 8; ++r) {
      const int kk = ((kq << 3) + r) << 2;
      const float4 v = *reinterpret_cast<const float4*>(xb + ((size_t)sc << 12) + k0 + kk);
      XT[(kk + 0) * 72 + sc] = v.x;
      XT[(kk + 1) * 72 + sc] = v.y;
      XT[(kk + 2) * 72 + sc] = v.z;
      XT[(kk + 3) * 72 + sc] = v.w;
    }
    __syncthreads();
    float accf[4][4];
#pragma unroll
    for (int i = 0; i < 4; ++i)
#pragma unroll
      for (int j = 0; j < 4; ++j) accf[i][j] = 0.0f;
    float rsf[4] = {0.f, 0.f, 0.f, 0.f};
#pragma unroll 2
    for (int kk = 0; kk < 128; ++kk) {
      const float4 a4 = *reinterpret_cast<const float4*>(XT + kk * 72 + (cg << 2));
      const float4 b4 = *reinterpret_cast<const float4*>(XT + kk * 72 + (dg << 2));
      const float a[4] = {a4.x, a4.y, a4.z, a4.w};
      const float b[4] = {b4.x, b4.y, b4.z, b4.w};
#pragma unroll
      for (int i = 0; i < 4; ++i) {
#pragma unroll
        for (int j = 0; j < 4; ++j) accf[i][j] = fmaf(a[i], b[j], accf[i][j]);
        rsf[i] += a[i];
      }
    }
#pragma unroll
    for (int i = 0; i < 4; ++i) {
#pragma unroll
      for (int j = 0; j < 4; ++j) acc[i][j] += (double)accf[i][j];
      rs[i] += (double)rsf[i];
    }
    __syncthreads();
  }
  const int c0 = cg << 2, d0 = dg << 2;
#pragma unroll
  for (int i = 0; i < 4; ++i)
#pragma unroll
    for (int j = 0; j < 4; ++j)
      atomicAdd(&S[(c0 + i) * 64 + d0 + j], acc[i][j]);
  if (dg == 0) {
#pragma unroll
    for (int i = 0; i < 4; ++i) atomicAdd(&rowsum[c0 + i], rs[i]);
  }
}

// Single block. One-sided (Hestenes) Jacobi, FULLY REGISTER-RESIDENT:
// lane l of wave 0 owns column l of G in 64 VGPRs. Per tournament round,
// fetch partner's column via 64 ds_bpermute (crossbar, conflict-free, no
// LDS writes, no barriers, no wave_barrier: cross-round deps are register
// deps in wave64 lockstep). apq is computed IDENTICALLY by both lanes of a
// pair (same products, same summation order -> bitwise equal -> consistent
// c,s) so there is NO cross-lane reduction at all.
__global__ __launch_bounds__(256) void zca_solve_k(const double* __restrict__ S,
                                                   const double* __restrict__ rowsum,
                                                   const float* __restrict__ weight,
                                                   const float* __restrict__ bias,
                                                   float* __restrict__ T,
                                                   float* __restrict__ offv) {
  __shared__ __align__(16) float G[64 * 68];  // column-major, col stride 68
  __shared__ float lam[64];
  __shared__ float msd[64];                   // mu/sig (f32)
  __shared__ float isg[64];                   // 1/sig (f32)
  __shared__ double mu[64], sig[64];
  __shared__ float wk2[64];                   // active * lam^(-5/2)
  __shared__ int idxs[64];
  const int t = threadIdx.x;
  const double n = 262144.0;

  if (t < 64) {
    const double m = rowsum[t] / n;
    const double var = (S[t * 64 + t] - n * m * m) / (n - 1.0);
    mu[t] = m;
    sig[t] = sqrt(var + 1e-5);
    msd[t] = (float)(m / sig[t]);
    isg[t] = (float)(1.0 / sig[t]);
  }
  __syncthreads();
  for (int e = t; e < 4096; e += 256) {
    const int col = e >> 6, row = e & 63;
    double v = (S[row * 64 + col] - n * mu[row] * mu[col]) / (n * sig[row] * sig[col]);
    if (row == col) v += 1e-5;
    G[col * 68 + row] = (float)v;
  }
  __syncthreads();

  if (t < 64) {  // ---- wave-0 register Jacobi: zero LDS traffic except bpermute ----
    float C[64];
#pragma unroll
    for (int i4 = 0; i4 < 16; ++i4) {
      const float4 v = *reinterpret_cast<const float4*>(G + t * 68 + (i4 << 2));
      C[4 * i4 + 0] = v.x; C[4 * i4 + 1] = v.y;
      C[4 * i4 + 2] = v.z; C[4 * i4 + 3] = v.w;
    }
    float nrm = 0.0f;
#pragma unroll
    for (int i = 0; i < 64; ++i) nrm = fmaf(C[i], C[i], nrm);

    for (int sweep = 0; sweep < 7; ++sweep) {
      int anyflag = 0;
      for (int r = 0; r < 63; ++r) {
        // round-robin tournament: partner lane + role (am I the "p" side?)
        int partner, rolep;
        if (t == 0) {
          int pp = 62 + r; if (pp >= 63) pp -= 63;
          partner = 1 + pp; rolep = 1;
        } else {
          int a = t - 1 - r; if (a < 0) a += 63;
          if (a == 62) { partner = 0; rolep = 0; }
          else {
            int pp = 61 - a + r; if (pp >= 63) pp -= 63;
            partner = 1 + pp;
            rolep = (a <= 30) ? 1 : 0;
          }
        }
        const float pn = __shfl(nrm, partner);
        float Q[64];
#pragma unroll
        for (int i = 0; i < 64; ++i) Q[i] = __shfl(C[i], partner);
        float s0 = 0.f, s1 = 0.f, s2 = 0.f, s3 = 0.f;
#pragma unroll
        for (int i = 0; i < 64; i += 4) {
          s0 = fmaf(C[i + 0], Q[i + 0], s0);
          s1 = fmaf(C[i + 1], Q[i + 1], s1);
          s2 = fmaf(C[i + 2], Q[i + 2], s2);
          s3 = fmaf(C[i + 3], Q[i + 3], s3);
        }
        const float apq = (s0 + s1) + (s2 + s3);  // bitwise-identical in both lanes
        const float app = rolep ? nrm : pn;
        const float aqq = rolep ? pn : nrm;
        if (apq * apq > 1e-11f * app * aqq) {
          anyflag = 1;
          const float tau = (aqq - app) / (2.0f * apq);
          const float tt = (tau >= 0.0f ? 1.0f : -1.0f) / (fabsf(tau) + sqrtf(1.0f + tau * tau));
          const float c = 1.0f / sqrtf(1.0f + tt * tt);
          const float ts = rolep ? -tt : tt;
          const float b = ts * c;  // rolep: -s (new p = c*p - s*q); else +s (new q = s*p + c*q)
          nrm = fmaf(ts, apq, nrm);
#pragma unroll
          for (int i = 0; i < 64; ++i) C[i] = fmaf(c, C[i], b * Q[i]);
        }
      }
      if (!__any(anyflag)) break;
    }

    // exact eigenvalue + publish column to LDS for the epilogue
    float sn = 0.0f;
#pragma unroll
    for (int i = 0; i < 64; ++i) sn = fmaf(C[i], C[i], sn);
    lam[t] = sqrtf(sn);
#pragma unroll
    for (int i4 = 0; i4 < 16; ++i4) {
      float4 v;
      v.x = C[4 * i4 + 0]; v.y = C[4 * i4 + 1];
      v.z = C[4 * i4 + 2]; v.w = C[4 * i4 + 3];
      *reinterpret_cast<float4*>(G + t * 68 + (i4 << 2)) = v;
    }
  }
  __syncthreads();

  if (t < 64) {
    const float e = lam[t];
    int rank = 0;
    for (int j = 0; j < 64; ++j) {
      const float ej = lam[j];
      if (ej > e || (ej == e && j < t)) ++rank;
    }
    idxs[rank] = t;
  }
  __syncthreads();
  if (t == 0) {
    double total = 0.0;
    for (int j = 0; j < 64; ++j) total += (double)lam[j];
    double cum = 0.0;
    bool done = false;
    for (int k = 0; k < 64; ++k) {
      const double l = (double)lam[idxs[k]];
      cum += l;
      double w = 0.0;
      if (k < 32 && !done) w = 1.0 / (sqrt(l) * l * l);  // lam^(-1/2) / lam^2
      if (cum / total >= 0.95) done = true;
      wk2[k] = (float)w;
    }
  }
  __syncthreads();
  // Wxr[c][d] = sum_k wk2[k] * G[c,idx_k] * G[d,idx_k]; fold into T and off.
  {
    const int c = t >> 2, db = (t & 3) << 4;
    float accf[16];
#pragma unroll
    for (int d = 0; d < 16; ++d) accf[d] = 0.0f;
    for (int k = 0; k < 32; ++k) {
      const int sk = idxs[k];
      const float vc = wk2[k] * G[sk * 68 + c];
      const float* gcol = G + sk * 68 + db;
#pragma unroll
      for (int d4 = 0; d4 < 4; ++d4) {
        const float4 v = *reinterpret_cast<const float4*>(gcol + (d4 << 2));
        accf[d4 * 4 + 0] = fmaf(vc, v.x, accf[d4 * 4 + 0]);
        accf[d4 * 4 + 1] = fmaf(vc, v.y, accf[d4 * 4 + 1]);
        accf[d4 * 4 + 2] = fmaf(vc, v.z, accf[d4 * 4 + 2]);
        accf[d4 * 4 + 3] = fmaf(vc, v.w, accf[d4 * 4 + 3]);
      }
    }
    const float wc = weight[c];
    float po = 0.0f;
#pragma unroll
    for (int d = 0; d < 16; ++d) {
      T[c * 64 + db + d] = wc * accf[d] * isg[db + d];
      po = fmaf(accf[d], msd[db + d], po);
    }
    po += __shfl_xor(po, 1);
    po += __shfl_xor(po, 2);
    if ((t & 3) == 0) offv[c] = bias[c] - wc * po;
  }
}

// out[n,c,k] = sum_d T[c][d]*x[n,d,k] + off[c].
// Grid 512: (n = b>>3, 512 k per block, 2 positions per thread).
__global__ __launch_bounds__(256) void zca_apply_k(const float* __restrict__ x,
                                                   const float* __restrict__ T,
                                                   const float* __restrict__ offv,
                                                   float* __restrict__ out) {
  __shared__ __align__(16) float4 Tl4[64 * 16];  // Tl4[c*16 + d4]
  __shared__ float offl[64];
  const int t = threadIdx.x;
  for (int e = t; e < 1024; e += 256) Tl4[e] = reinterpret_cast<const float4*>(T)[e];
  if (t < 64) offl[t] = offv[t];
  __syncthreads();
  const int n = blockIdx.x >> 3;
  const int k0 = ((blockIdx.x & 7) << 9) + (t << 1);
  const float* xb = x + ((size_t)n << 18) + k0;
  float2 acc[64];
#pragma unroll
  for (int c = 0; c < 64; ++c) { acc[c].x = offl[c]; acc[c].y = offl[c]; }
  float2 xv[4];
#pragma unroll
  for (int dd = 0; dd < 4; ++dd)
    xv[dd] = *reinterpret_cast<const float2*>(xb + ((size_t)dd << 12));
  for (int d4 = 0; d4 < 16; ++d4) {
    float2 xn[4];
    if (d4 < 15) {
#pragma unroll
      for (int dd = 0; dd < 4; ++dd)
        xn[dd] = *reinterpret_cast<const float2*>(xb + ((size_t)((d4 + 1) * 4 + dd) << 12));
    }
#pragma unroll
    for (int c = 0; c < 64; ++c) {
      const float4 tv = Tl4[(c << 4) + d4];
      acc[c].x = fmaf(tv.x, xv[0].x, acc[c].x); acc[c].y = fmaf(tv.x, xv[0].y, acc[c].y);
      acc[c].x = fmaf(tv.y, xv[1].x, acc[c].x); acc[c].y = fmaf(tv.y, xv[1].y, acc[c].y);
      acc[c].x = fmaf(tv.z, xv[2].x, acc[c].x); acc[c].y = fmaf(tv.z, xv[2].y, acc[c].y);
      acc[c].x = fmaf(tv.w, xv[3].x, acc[c].x); acc[c].y = fmaf(tv.w, xv[3].y, acc[c].y);
    }
#pragma unroll
    for (int dd = 0; dd < 4; ++dd) xv[dd] = xn[dd];
  }
  float* ob = out + ((size_t)n << 18) + k0;
#pragma unroll
  for (int c = 0; c < 64; ++c)
    *reinterpret_cast<float2*>(ob + ((size_t)c << 12)) = acc[c];
}

extern "C" void kernel_launch(void* const* d_in, const int* in_sizes, int n_in,
                              void* d_out, int out_size, void* d_ws, size_t ws_size,
                              hipStream_t stream) {
  const float* x = (const float*)d_in[0];
  const float* weight = (const float*)d_in[1];
  const float* bias = (const float*)d_in[2];
  float* out = (float*)d_out;
  char* ws = (char*)d_ws;
  double* S = (double*)ws;
  double* rowsum = (double*)(ws + 32768);
  float* T = (float*)(ws + 33280);
  float* offv = (float*)(ws + 49664);

  hipMemsetAsync(S, 0, 33280, stream);  // S + rowsum (graph-capturable)
  hipLaunchKernelGGL(zca_gram_k, dim3(512), dim3(256), 0, stream, x, S, rowsum);
  hipLaunchKernelGGL(zca_solve_k, dim3(1), dim3(256), 0, stream, S, rowsum, weight, bias, T, offv);
  hipLaunchKernelGGL(zca_apply_k, dim3(512), dim3(256), 0, stream, x, T, offv, out);
}

// Round 6
// 536.465 us; speedup vs baseline: 1.2835x; 1.2835x over previous
//
#include <hip/hip_runtime.h>

// Problem: N=C=H=W=64. n = N*H*W = 262144 samples per channel.
// ws layout:
//   [0,     32768)  S      double[64*64]   Gram accumulator
//   [32768, 33280)  rowsum double[64]
//   [33280, 49664)  T      float[64*64]    folded transform
//   [49664, 49920)  off    float[64]       folded offset

// Gram + row sums. Grid 512: (n = b>>3, hw eighth = b&7). 4 tiles of 128.
// Tile staged TRANSPOSED: XT[kk][c] so both operand fragments are b128 reads.
__global__ __launch_bounds__(256) void zca_gram_k(const float* __restrict__ x,
                                                  double* __restrict__ S,
                                                  double* __restrict__ rowsum) {
  __shared__ float XT[128 * 72];  // row kk (stride 72), 64 channels
  const int t = threadIdx.x;
  const int n = blockIdx.x >> 3;
  const int k0base = (blockIdx.x & 7) << 9;
  const float* xb = x + ((size_t)n << 18);
  const int cg = t >> 4, dg = t & 15;
  const int sc = t & 63, kq = t >> 6;

  double acc[4][4];
#pragma unroll
  for (int i = 0; i < 4; ++i)
#pragma unroll
    for (int j = 0; j < 4; ++j) acc[i][j] = 0.0;
  double rs[4] = {0.0, 0.0, 0.0, 0.0};

  for (int tile = 0; tile < 4; ++tile) {
    const int k0 = k0base + (tile << 7);
#pragma unroll
    for (int r = 0; r < 8; ++r) {
      const int kk = ((kq << 3) + r) << 2;
      const float4 v = *reinterpret_cast<const float4*>(xb + ((size_t)sc << 12) + k0 + kk);
      XT[(kk + 0) * 72 + sc] = v.x;
      XT[(kk + 1) * 72 + sc] = v.y;
      XT[(kk + 2) * 72 + sc] = v.z;
      XT[(kk + 3) * 72 + sc] = v.w;
    }
    __syncthreads();
    float accf[4][4];
#pragma unroll
    for (int i = 0; i < 4; ++i)
#pragma unroll
      for (int j = 0; j < 4; ++j) accf[i][j] = 0.0f;
    float rsf[4] = {0.f, 0.f, 0.f, 0.f};
#pragma unroll 2
    for (int kk = 0; kk < 128; ++kk) {
      const float4 a4 = *reinterpret_cast<const float4*>(XT + kk * 72 + (cg << 2));
      const float4 b4 = *reinterpret_cast<const float4*>(XT + kk * 72 + (dg << 2));
      const float a[4] = {a4.x, a4.y, a4.z, a4.w};
      const float b[4] = {b4.x, b4.y, b4.z, b4.w};
#pragma unroll
      for (int i = 0; i < 4; ++i) {
#pragma unroll
        for (int j = 0; j < 4; ++j) accf[i][j] = fmaf(a[i], b[j], accf[i][j]);
        rsf[i] += a[i];
      }
    }
#pragma unroll
    for (int i = 0; i < 4; ++i) {
#pragma unroll
      for (int j = 0; j < 4; ++j) acc[i][j] += (double)accf[i][j];
      rs[i] += (double)rsf[i];
    }
    __syncthreads();
  }
  const int c0 = cg << 2, d0 = dg << 2;
#pragma unroll
  for (int i = 0; i < 4; ++i)
#pragma unroll
    for (int j = 0; j < 4; ++j)
      atomicAdd(&S[(c0 + i) * 64 + d0 + j], acc[i][j]);
  if (dg == 0) {
#pragma unroll
    for (int i = 0; i < 4; ++i) atomicAdd(&rowsum[c0 + i], rs[i]);
  }
}

// round-robin tournament pairing: 32 disjoint pairs covering all 64 indices.
__device__ __forceinline__ void zca_sched(int j, int r, int& p, int& q) {
  if (j == 0) {
    p = 0;
    int a = 62 + r; if (a >= 63) a -= 63;
    q = 1 + a;
  } else {
    int a = j - 1 + r;  if (a >= 63) a -= 63;
    int b = 62 - j + r; if (b >= 63) b -= 63;
    p = 1 + a;
    q = 1 + b;
  }
}

// DPP quad_perm [1,0,3,2]: add value from lane^1 — pure VALU, no LDS.
// Both lanes get (mine + partner): IEEE add is commutative -> bitwise equal.
__device__ __forceinline__ float zca_dpp_xor1_add(float v) {
  const int vi = __builtin_bit_cast(int, v);
  const int pi = __builtin_amdgcn_update_dpp(vi, vi, 0xB1, 0xF, 0xF, true);
  return v + __builtin_bit_cast(float, pi);
}

// Single block. One-sided (Hestenes) Jacobi on columns of G = M0, f32,
// run by ONE WAVE (2 lanes/pair, 32 elems/lane), zero barriers in the loop.
// All pair quantities (app, aqq, apq) computed EXACTLY from the loaded
// slices and reduced with one DPP add each — no shfl, no norms in LDS.
// No V matrix: at convergence G = M0*V, so v_i = G[:,i]/||G[:,i]||.
__global__ __launch_bounds__(256) void zca_solve_k(const double* __restrict__ S,
                                                   const double* __restrict__ rowsum,
                                                   const float* __restrict__ weight,
                                                   const float* __restrict__ bias,
                                                   float* __restrict__ T,
                                                   float* __restrict__ offv) {
  __shared__ __align__(16) float G[64 * 68];  // column-major, col stride 68
  __shared__ float lam[64];
  __shared__ float msd[64];                   // mu/sig (f32)
  __shared__ float isg[64];                   // 1/sig (f32)
  __shared__ double mu[64], sig[64];
  __shared__ float wk2[64];                   // active * lam^(-5/2)
  __shared__ int idxs[64];
  const int t = threadIdx.x;
  const double n = 262144.0;

  if (t < 64) {
    const double m = rowsum[t] / n;
    const double var = (S[t * 64 + t] - n * m * m) / (n - 1.0);
    mu[t] = m;
    sig[t] = sqrt(var + 1e-5);
    msd[t] = (float)(m / sig[t]);
    isg[t] = (float)(1.0 / sig[t]);
  }
  __syncthreads();
  for (int e = t; e < 4096; e += 256) {
    const int col = e >> 6, row = e & 63;
    double v = (S[row * 64 + col] - n * mu[row] * mu[col]) / (n * sig[row] * sig[col]);
    if (row == col) v += 1e-5;
    G[col * 68 + row] = (float)v;
  }
  __syncthreads();

  if (t < 64) {  // ---- single-wave Jacobi: LDS slices + DPP reduce ----
    const int g = t >> 1;
    const int o = (t & 1) << 5;  // 32 elements per lane
    for (int sweep = 0; sweep < 7; ++sweep) {
      int anyflag = 0;
      for (int r = 0; r < 63; ++r) {
        int p, q;
        zca_sched(g, r, p, q);
        float* Gp = G + p * 68 + o;
        float* Gq = G + q * 68 + o;
        float4 P[8], Q[8];
#pragma unroll
        for (int i = 0; i < 8; ++i) P[i] = *reinterpret_cast<float4*>(Gp + (i << 2));
#pragma unroll
        for (int i = 0; i < 8; ++i) Q[i] = *reinterpret_cast<float4*>(Gq + (i << 2));
        float a0 = 0.f, a1 = 0.f, b0 = 0.f, b1 = 0.f, c0 = 0.f, c1 = 0.f;
#pragma unroll
        for (int i = 0; i < 8; ++i) {
          a0 = fmaf(P[i].x, P[i].x, a0); a1 = fmaf(P[i].y, P[i].y, a1);
          a0 = fmaf(P[i].z, P[i].z, a0); a1 = fmaf(P[i].w, P[i].w, a1);
          b0 = fmaf(Q[i].x, Q[i].x, b0); b1 = fmaf(Q[i].y, Q[i].y, b1);
          b0 = fmaf(Q[i].z, Q[i].z, b0); b1 = fmaf(Q[i].w, Q[i].w, b1);
          c0 = fmaf(P[i].x, Q[i].x, c0); c1 = fmaf(P[i].y, Q[i].y, c1);
          c0 = fmaf(P[i].z, Q[i].z, c0); c1 = fmaf(P[i].w, Q[i].w, c1);
        }
        const float app = zca_dpp_xor1_add(a0 + a1);
        const float aqq = zca_dpp_xor1_add(b0 + b1);
        const float apq = zca_dpp_xor1_add(c0 + c1);
        if (apq * apq > 1e-11f * app * aqq) {
          anyflag = 1;
          const float tau = (aqq - app) / (2.0f * apq);
          const float tt = (tau >= 0.0f ? 1.0f : -1.0f) / (fabsf(tau) + sqrtf(1.0f + tau * tau));
          const float c = 1.0f / sqrtf(1.0f + tt * tt);
          const float s = tt * c;
#pragma unroll
          for (int i = 0; i < 8; ++i) {
            float4 np, nq;
            np.x = c * P[i].x - s * Q[i].x; np.y = c * P[i].y - s * Q[i].y;
            np.z = c * P[i].z - s * Q[i].z; np.w = c * P[i].w - s * Q[i].w;
            nq.x = s * P[i].x + c * Q[i].x; nq.y = s * P[i].y + c * Q[i].y;
            nq.z = s * P[i].z + c * Q[i].z; nq.w = s * P[i].w + c * Q[i].w;
            *reinterpret_cast<float4*>(Gp + (i << 2)) = np;
            *reinterpret_cast<float4*>(Gq + (i << 2)) = nq;
          }
        }
        __builtin_amdgcn_wave_barrier();  // pin LDS program order across rounds
      }
      if (!__any(anyflag)) break;
    }
  }
  __syncthreads();

  // eigenvalues = exact column norms of converged G (G[:,i] = lam_i * v_i)
  if (t < 64) {
    float s = 0.0f;
#pragma unroll
    for (int j4 = 0; j4 < 16; ++j4) {
      const float4 v = *reinterpret_cast<const float4*>(G + t * 68 + (j4 << 2));
      s = fmaf(v.x, v.x, s); s = fmaf(v.y, v.y, s);
      s = fmaf(v.z, v.z, s); s = fmaf(v.w, v.w, s);
    }
    lam[t] = sqrtf(s);
  }
  __syncthreads();
  if (t < 64) {
    const float e = lam[t];
    int rank = 0;
    for (int j = 0; j < 64; ++j) {
      const float ej = lam[j];
      if (ej > e || (ej == e && j < t)) ++rank;
    }
    idxs[rank] = t;
  }
  __syncthreads();
  if (t == 0) {
    double total = 0.0;
    for (int j = 0; j < 64; ++j) total += (double)lam[j];
    double cum = 0.0;
    bool done = false;
    for (int k = 0; k < 64; ++k) {
      const double l = (double)lam[idxs[k]];
      cum += l;
      double w = 0.0;
      if (k < 32 && !done) w = 1.0 / (sqrt(l) * l * l);  // lam^(-1/2) / lam^2
      if (cum / total >= 0.95) done = true;
      wk2[k] = (float)w;
    }
  }
  __syncthreads();
  // Wxr[c][d] = sum_k wk2[k] * G[c,idx_k] * G[d,idx_k]; fold into T and off.
  {
    const int c = t >> 2, db = (t & 3) << 4;
    float accf[16];
#pragma unroll
    for (int d = 0; d < 16; ++d) accf[d] = 0.0f;
    for (int k = 0; k < 32; ++k) {
      const int sk = idxs[k];
      const float vc = wk2[k] * G[sk * 68 + c];
      const float* gcol = G + sk * 68 + db;
#pragma unroll
      for (int d4 = 0; d4 < 4; ++d4) {
        const float4 v = *reinterpret_cast<const float4*>(gcol + (d4 << 2));
        accf[d4 * 4 + 0] = fmaf(vc, v.x, accf[d4 * 4 + 0]);
        accf[d4 * 4 + 1] = fmaf(vc, v.y, accf[d4 * 4 + 1]);
        accf[d4 * 4 + 2] = fmaf(vc, v.z, accf[d4 * 4 + 2]);
        accf[d4 * 4 + 3] = fmaf(vc, v.w, accf[d4 * 4 + 3]);
      }
    }
    const float wc = weight[c];
    float po = 0.0f;
#pragma unroll
    for (int d = 0; d < 16; ++d) {
      T[c * 64 + db + d] = wc * accf[d] * isg[db + d];
      po = fmaf(accf[d], msd[db + d], po);
    }
    po += __shfl_xor(po, 1);
    po += __shfl_xor(po, 2);
    if ((t & 3) == 0) offv[c] = bias[c] - wc * po;
  }
}

// out[n,c,k] = sum_d T[c][d]*x[n,d,k] + off[c].
// Grid 512: (n = b>>3, 512 k per block, 2 positions per thread).
__global__ __launch_bounds__(256) void zca_apply_k(const float* __restrict__ x,
                                                   const float* __restrict__ T,
                                                   const float* __restrict__ offv,
                                                   float* __restrict__ out) {
  __shared__ __align__(16) float4 Tl4[64 * 16];  // Tl4[c*16 + d4]
  __shared__ float offl[64];
  const int t = threadIdx.x;
  for (int e = t; e < 1024; e += 256) Tl4[e] = reinterpret_cast<const float4*>(T)[e];
  if (t < 64) offl[t] = offv[t];
  __syncthreads();
  const int n = blockIdx.x >> 3;
  const int k0 = ((blockIdx.x & 7) << 9) + (t << 1);
  const float* xb = x + ((size_t)n << 18) + k0;
  float2 acc[64];
#pragma unroll
  for (int c = 0; c < 64; ++c) { acc[c].x = offl[c]; acc[c].y = offl[c]; }
  float2 xv[4];
#pragma unroll
  for (int dd = 0; dd < 4; ++dd)
    xv[dd] = *reinterpret_cast<const float2*>(xb + ((size_t)dd << 12));
  for (int d4 = 0; d4 < 16; ++d4) {
    float2 xn[4];
    if (d4 < 15) {
#pragma unroll
      for (int dd = 0; dd < 4; ++dd)
        xn[dd] = *reinterpret_cast<const float2*>(xb + ((size_t)((d4 + 1) * 4 + dd) << 12));
    }
#pragma unroll
    for (int c = 0; c < 64; ++c) {
      const float4 tv = Tl4[(c << 4) + d4];
      acc[c].x = fmaf(tv.x, xv[0].x, acc[c].x); acc[c].y = fmaf(tv.x, xv[0].y, acc[c].y);
      acc[c].x = fmaf(tv.y, xv[1].x, acc[c].x); acc[c].y = fmaf(tv.y, xv[1].y, acc[c].y);
      acc[c].x = fmaf(tv.z, xv[2].x, acc[c].x); acc[c].y = fmaf(tv.z, xv[2].y, acc[c].y);
      acc[c].x = fmaf(tv.w, xv[3].x, acc[c].x); acc[c].y = fmaf(tv.w, xv[3].y, acc[c].y);
    }
#pragma unroll
    for (int dd = 0; dd < 4; ++dd) xv[dd] = xn[dd];
  }
  float* ob = out + ((size_t)n << 18) + k0;
#pragma unroll
  for (int c = 0; c < 64; ++c)
    *reinterpret_cast<float2*>(ob + ((size_t)c << 12)) = acc[c];
}

extern "C" void kernel_launch(void* const* d_in, const int* in_sizes, int n_in,
                              void* d_out, int out_size, void* d_ws, size_t ws_size,
                              hipStream_t stream) {
  const float* x = (const float*)d_in[0];
  const float* weight = (const float*)d_in[1];
  const float* bias = (const float*)d_in[2];
  float* out = (float*)d_out;
  char* ws = (char*)d_ws;
  double* S = (double*)ws;
  double* rowsum = (double*)(ws + 32768);
  float* T = (float*)(ws + 33280);
  float* offv = (float*)(ws + 49664);

  hipMemsetAsync(S, 0, 33280, stream);  // S + rowsum (graph-capturable)
  hipLaunchKernelGGL(zca_gram_k, dim3(512), dim3(256), 0, stream, x, S, rowsum);
  hipLaunchKernelGGL(zca_solve_k, dim3(1), dim3(256), 0, stream, S, rowsum, weight, bias, T, offv);
  hipLaunchKernelGGL(zca_apply_k, dim3(512), dim3(256), 0, stream, x, T, offv, out);
}

// Round 7
// 495.778 us; speedup vs baseline: 1.3889x; 1.0821x over previous
//
#include <hip/hip_runtime.h>

// Problem: N=C=H=W=64. n = N*H*W = 262144 samples per channel.
// ws layout:
//   [0,     32768)  S      double[64*64]   Gram accumulator
//   [32768, 33280)  rowsum double[64]
//   [33280, 49664)  T      float[64*64]    folded transform
//   [49664, 49920)  off    float[64]       folded offset

// Gram + row sums. Grid 512: (n = b>>3, hw eighth = b&7). 4 tiles of 128.
// Tile staged TRANSPOSED: XT[kk][c] so both operand fragments are b128 reads.
__global__ __launch_bounds__(256) void zca_gram_k(const float* __restrict__ x,
                                                  double* __restrict__ S,
                                                  double* __restrict__ rowsum) {
  __shared__ float XT[128 * 72];  // row kk (stride 72), 64 channels
  const int t = threadIdx.x;
  const int n = blockIdx.x >> 3;
  const int k0base = (blockIdx.x & 7) << 9;
  const float* xb = x + ((size_t)n << 18);
  const int cg = t >> 4, dg = t & 15;
  const int sc = t & 63, kq = t >> 6;

  double acc[4][4];
#pragma unroll
  for (int i = 0; i < 4; ++i)
#pragma unroll
    for (int j = 0; j < 4; ++j) acc[i][j] = 0.0;
  double rs[4] = {0.0, 0.0, 0.0, 0.0};

  for (int tile = 0; tile < 4; ++tile) {
    const int k0 = k0base + (tile << 7);
#pragma unroll
    for (int r = 0; r < 8; ++r) {
      const int kk = ((kq << 3) + r) << 2;
      const float4 v = *reinterpret_cast<const float4*>(xb + ((size_t)sc << 12) + k0 + kk);
      XT[(kk + 0) * 72 + sc] = v.x;
      XT[(kk + 1) * 72 + sc] = v.y;
      XT[(kk + 2) * 72 + sc] = v.z;
      XT[(kk + 3) * 72 + sc] = v.w;
    }
    __syncthreads();
    float accf[4][4];
#pragma unroll
    for (int i = 0; i < 4; ++i)
#pragma unroll
      for (int j = 0; j < 4; ++j) accf[i][j] = 0.0f;
    float rsf[4] = {0.f, 0.f, 0.f, 0.f};
#pragma unroll 2
    for (int kk = 0; kk < 128; ++kk) {
      const float4 a4 = *reinterpret_cast<const float4*>(XT + kk * 72 + (cg << 2));
      const float4 b4 = *reinterpret_cast<const float4*>(XT + kk * 72 + (dg << 2));
      const float a[4] = {a4.x, a4.y, a4.z, a4.w};
      const float b[4] = {b4.x, b4.y, b4.z, b4.w};
#pragma unroll
      for (int i = 0; i < 4; ++i) {
#pragma unroll
        for (int j = 0; j < 4; ++j) accf[i][j] = fmaf(a[i], b[j], accf[i][j]);
        rsf[i] += a[i];
      }
    }
#pragma unroll
    for (int i = 0; i < 4; ++i) {
#pragma unroll
      for (int j = 0; j < 4; ++j) acc[i][j] += (double)accf[i][j];
      rs[i] += (double)rsf[i];
    }
    __syncthreads();
  }
  const int c0 = cg << 2, d0 = dg << 2;
#pragma unroll
  for (int i = 0; i < 4; ++i)
#pragma unroll
    for (int j = 0; j < 4; ++j)
      atomicAdd(&S[(c0 + i) * 64 + d0 + j], acc[i][j]);
  if (dg == 0) {
#pragma unroll
    for (int i = 0; i < 4; ++i) atomicAdd(&rowsum[c0 + i], rs[i]);
  }
}

// round-robin tournament pairing: 32 disjoint pairs covering all 64 indices.
__device__ __forceinline__ void zca_sched(int j, int r, int& p, int& q) {
  if (j == 0) {
    p = 0;
    int a = 62 + r; if (a >= 63) a -= 63;
    q = 1 + a;
  } else {
    int a = j - 1 + r;  if (a >= 63) a -= 63;
    int b = 62 - j + r; if (b >= 63) b -= 63;
    p = 1 + a;
    q = 1 + b;
  }
}

// DPP quad_perm [1,0,3,2]: fetch value from lane^1 — pure VALU, no LDS.
__device__ __forceinline__ float zca_dpp_xor1(float v) {
  const int vi = __builtin_bit_cast(int, v);
  const int pi = __builtin_amdgcn_update_dpp(vi, vi, 0xB1, 0xF, 0xF, true);
  return __builtin_bit_cast(float, pi);
}

// Single block. One-sided (Hestenes) Jacobi on columns of G = M0, f32,
// run by ONE WAVE (2 lanes/pair, 32 elems/lane), zero barriers in the loop.
// Round-4 structure (empirically best round time): incremental norms in LDS,
// apq-only dot (32 FMA). DPP replaces both LDS-pipe exchanges (apq reduce,
// partner-norm share). Skip threshold raised to 1e-10 rel so the ballot
// exit can fire once converged (skipped rounds do no rotate/write).
// No V matrix: at convergence G = M0*V, so v_i = G[:,i]/||G[:,i]||.
__global__ __launch_bounds__(256) void zca_solve_k(const double* __restrict__ S,
                                                   const double* __restrict__ rowsum,
                                                   const float* __restrict__ weight,
                                                   const float* __restrict__ bias,
                                                   float* __restrict__ T,
                                                   float* __restrict__ offv) {
  __shared__ __align__(16) float G[64 * 68];  // column-major, col stride 68
  __shared__ float norms[64];                 // running squared col norms
  __shared__ float lam[64];
  __shared__ float msd[64];                   // mu/sig (f32)
  __shared__ float isg[64];                   // 1/sig (f32)
  __shared__ double mu[64], sig[64];
  __shared__ float wk2[64];                   // active * lam^(-5/2)
  __shared__ int idxs[64];
  const int t = threadIdx.x;
  const double n = 262144.0;

  if (t < 64) {
    const double m = rowsum[t] / n;
    const double var = (S[t * 64 + t] - n * m * m) / (n - 1.0);
    mu[t] = m;
    sig[t] = sqrt(var + 1e-5);
    msd[t] = (float)(m / sig[t]);
    isg[t] = (float)(1.0 / sig[t]);
  }
  __syncthreads();
  for (int e = t; e < 4096; e += 256) {
    const int col = e >> 6, row = e & 63;
    double v = (S[row * 64 + col] - n * mu[row] * mu[col]) / (n * sig[row] * sig[col]);
    if (row == col) v += 1e-5;
    G[col * 68 + row] = (float)v;
  }
  __syncthreads();
  if (t < 64) {  // initial squared column norms
    float s = 0.0f;
#pragma unroll
    for (int j4 = 0; j4 < 16; ++j4) {
      const float4 v = *reinterpret_cast<const float4*>(G + t * 68 + (j4 << 2));
      s = fmaf(v.x, v.x, s); s = fmaf(v.y, v.y, s);
      s = fmaf(v.z, v.z, s); s = fmaf(v.w, v.w, s);
    }
    norms[t] = s;
  }
  __syncthreads();

  if (t < 64) {  // ---- single-wave Jacobi: LDS slices + DPP exchanges ----
    const int g = t >> 1;
    const int side = t & 1;      // 0 = p-side, 1 = q-side
    const int o = side << 5;     // 32 elements per lane
    for (int sweep = 0; sweep < 7; ++sweep) {
      int anyflag = 0;
      for (int r = 0; r < 63; ++r) {
        int p, q;
        zca_sched(g, r, p, q);
        const int mycol = side ? q : p;
        const float myn = norms[mycol];          // 1 LDS read/lane
        float* Gp = G + p * 68 + o;
        float* Gq = G + q * 68 + o;
        float4 P[8], Q[8];
#pragma unroll
        for (int i = 0; i < 8; ++i) P[i] = *reinterpret_cast<float4*>(Gp + (i << 2));
#pragma unroll
        for (int i = 0; i < 8; ++i) Q[i] = *reinterpret_cast<float4*>(Gq + (i << 2));
        float s0 = 0.f, s1 = 0.f, s2 = 0.f, s3 = 0.f;
#pragma unroll
        for (int i = 0; i < 8; ++i) {
          s0 = fmaf(P[i].x, Q[i].x, s0);
          s1 = fmaf(P[i].y, Q[i].y, s1);
          s2 = fmaf(P[i].z, Q[i].z, s2);
          s3 = fmaf(P[i].w, Q[i].w, s3);
        }
        const float part = (s0 + s1) + (s2 + s3);
        const float apq = part + zca_dpp_xor1(part);   // bitwise-equal in pair
        const float othern = zca_dpp_xor1(myn);
        const float app = side ? othern : myn;
        const float aqq = side ? myn : othern;
        if (apq * apq > 1e-10f * app * aqq) {
          anyflag = 1;
          const float tau = (aqq - app) / (2.0f * apq);
          const float tt = (tau >= 0.0f ? 1.0f : -1.0f) / (fabsf(tau) + sqrtf(1.0f + tau * tau));
          const float c = 1.0f / sqrtf(1.0f + tt * tt);
          const float s = tt * c;
#pragma unroll
          for (int i = 0; i < 8; ++i) {
            float4 np, nq;
            np.x = c * P[i].x - s * Q[i].x; np.y = c * P[i].y - s * Q[i].y;
            np.z = c * P[i].z - s * Q[i].z; np.w = c * P[i].w - s * Q[i].w;
            nq.x = s * P[i].x + c * Q[i].x; nq.y = s * P[i].y + c * Q[i].y;
            nq.z = s * P[i].z + c * Q[i].z; nq.w = s * P[i].w + c * Q[i].w;
            *reinterpret_cast<float4*>(Gp + (i << 2)) = np;
            *reinterpret_cast<float4*>(Gq + (i << 2)) = nq;
          }
          // side0 owns norms[p] (-= tt*apq), side1 owns norms[q] (+= tt*apq)
          norms[mycol] = fmaf(side ? tt : -tt, apq, myn);
        }
        __builtin_amdgcn_wave_barrier();  // pin LDS program order across rounds
      }
      if (!__any(anyflag)) break;
    }
  }
  __syncthreads();

  // eigenvalues = exact column norms of converged G (G[:,i] = lam_i * v_i)
  if (t < 64) {
    float s = 0.0f;
#pragma unroll
    for (int j4 = 0; j4 < 16; ++j4) {
      const float4 v = *reinterpret_cast<const float4*>(G + t * 68 + (j4 << 2));
      s = fmaf(v.x, v.x, s); s = fmaf(v.y, v.y, s);
      s = fmaf(v.z, v.z, s); s = fmaf(v.w, v.w, s);
    }
    lam[t] = sqrtf(s);
  }
  __syncthreads();
  if (t < 64) {
    const float e = lam[t];
    int rank = 0;
    for (int j = 0; j < 64; ++j) {
      const float ej = lam[j];
      if (ej > e || (ej == e && j < t)) ++rank;
    }
    idxs[rank] = t;
  }
  __syncthreads();
  if (t == 0) {
    double total = 0.0;
    for (int j = 0; j < 64; ++j) total += (double)lam[j];
    double cum = 0.0;
    bool done = false;
    for (int k = 0; k < 64; ++k) {
      const double l = (double)lam[idxs[k]];
      cum += l;
      double w = 0.0;
      if (k < 32 && !done) w = 1.0 / (sqrt(l) * l * l);  // lam^(-1/2) / lam^2
      if (cum / total >= 0.95) done = true;
      wk2[k] = (float)w;
    }
  }
  __syncthreads();
  // Wxr[c][d] = sum_k wk2[k] * G[c,idx_k] * G[d,idx_k]; fold into T and off.
  {
    const int c = t >> 2, db = (t & 3) << 4;
    float accf[16];
#pragma unroll
    for (int d = 0; d < 16; ++d) accf[d] = 0.0f;
    for (int k = 0; k < 32; ++k) {
      const int sk = idxs[k];
      const float vc = wk2[k] * G[sk * 68 + c];
      const float* gcol = G + sk * 68 + db;
#pragma unroll
      for (int d4 = 0; d4 < 4; ++d4) {
        const float4 v = *reinterpret_cast<const float4*>(gcol + (d4 << 2));
        accf[d4 * 4 + 0] = fmaf(vc, v.x, accf[d4 * 4 + 0]);
        accf[d4 * 4 + 1] = fmaf(vc, v.y, accf[d4 * 4 + 1]);
        accf[d4 * 4 + 2] = fmaf(vc, v.z, accf[d4 * 4 + 2]);
        accf[d4 * 4 + 3] = fmaf(vc, v.w, accf[d4 * 4 + 3]);
      }
    }
    const float wc = weight[c];
    float po = 0.0f;
#pragma unroll
    for (int d = 0; d < 16; ++d) {
      T[c * 64 + db + d] = wc * accf[d] * isg[db + d];
      po = fmaf(accf[d], msd[db + d], po);
    }
    po += __shfl_xor(po, 1);
    po += __shfl_xor(po, 2);
    if ((t & 3) == 0) offv[c] = bias[c] - wc * po;
  }
}

// out[n,c,k] = sum_d T[c][d]*x[n,d,k] + off[c].
// Grid 512: (n = b>>3, 512 k per block, 2 positions per thread).
__global__ __launch_bounds__(256) void zca_apply_k(const float* __restrict__ x,
                                                   const float* __restrict__ T,
                                                   const float* __restrict__ offv,
                                                   float* __restrict__ out) {
  __shared__ __align__(16) float4 Tl4[64 * 16];  // Tl4[c*16 + d4]
  __shared__ float offl[64];
  const int t = threadIdx.x;
  for (int e = t; e < 1024; e += 256) Tl4[e] = reinterpret_cast<const float4*>(T)[e];
  if (t < 64) offl[t] = offv[t];
  __syncthreads();
  const int n = blockIdx.x >> 3;
  const int k0 = ((blockIdx.x & 7) << 9) + (t << 1);
  const float* xb = x + ((size_t)n << 18) + k0;
  float2 acc[64];
#pragma unroll
  for (int c = 0; c < 64; ++c) { acc[c].x = offl[c]; acc[c].y = offl[c]; }
  float2 xv[4];
#pragma unroll
  for (int dd = 0; dd < 4; ++dd)
    xv[dd] = *reinterpret_cast<const float2*>(xb + ((size_t)dd << 12));
  for (int d4 = 0; d4 < 16; ++d4) {
    float2 xn[4];
    if (d4 < 15) {
#pragma unroll
      for (int dd = 0; dd < 4; ++dd)
        xn[dd] = *reinterpret_cast<const float2*>(xb + ((size_t)((d4 + 1) * 4 + dd) << 12));
    }
#pragma unroll
    for (int c = 0; c < 64; ++c) {
      const float4 tv = Tl4[(c << 4) + d4];
      acc[c].x = fmaf(tv.x, xv[0].x, acc[c].x); acc[c].y = fmaf(tv.x, xv[0].y, acc[c].y);
      acc[c].x = fmaf(tv.y, xv[1].x, acc[c].x); acc[c].y = fmaf(tv.y, xv[1].y, acc[c].y);
      acc[c].x = fmaf(tv.z, xv[2].x, acc[c].x); acc[c].y = fmaf(tv.z, xv[2].y, acc[c].y);
      acc[c].x = fmaf(tv.w, xv[3].x, acc[c].x); acc[c].y = fmaf(tv.w, xv[3].y, acc[c].y);
    }
#pragma unroll
    for (int dd = 0; dd < 4; ++dd) xv[dd] = xn[dd];
  }
  float* ob = out + ((size_t)n << 18) + k0;
#pragma unroll
  for (int c = 0; c < 64; ++c)
    *reinterpret_cast<float2*>(ob + ((size_t)c << 12)) = acc[c];
}

extern "C" void kernel_launch(void* const* d_in, const int* in_sizes, int n_in,
                              void* d_out, int out_size, void* d_ws, size_t ws_size,
                              hipStream_t stream) {
  const float* x = (const float*)d_in[0];
  const float* weight = (const float*)d_in[1];
  const float* bias = (const float*)d_in[2];
  float* out = (float*)d_out;
  char* ws = (char*)d_ws;
  double* S = (double*)ws;
  double* rowsum = (double*)(ws + 32768);
  float* T = (float*)(ws + 33280);
  float* offv = (float*)(ws + 49664);

  hipMemsetAsync(S, 0, 33280, stream);  // S + rowsum (graph-capturable)
  hipLaunchKernelGGL(zca_gram_k, dim3(512), dim3(256), 0, stream, x, S, rowsum);
  hipLaunchKernelGGL(zca_solve_k, dim3(1), dim3(256), 0, stream, S, rowsum, weight, bias, T, offv);
  hipLaunchKernelGGL(zca_apply_k, dim3(512), dim3(256), 0, stream, x, T, offv, out);
}